// Round 5
// baseline (343.082 us; speedup 1.0000x reference)
//
#include <hip/hip_runtime.h>

#define NUM_GRAPHS 1024
#define F_DIM 512

// Workspace layout: A[g*8 + j] for j=0..6 = per-graph feature-dot sums,
// A[g*8 + 7] = node count for graph g. Total 1024*8 floats = 32 KB.

__global__ void zero_ws_kernel(float* __restrict__ A, int n) {
    int i = blockIdx.x * blockDim.x + threadIdx.x;
    if (i < n) A[i] = 0.0f;
}

// Flush one segment: dot the raw per-lane feature sums sa[8] with W rows
// (read straight from global; W is 14 KB and L2-resident — flushes are rare),
// wave-reduce, atomically accumulate, reset sa.
__device__ __forceinline__ void flush_segment(float (&sa)[8], int seg_cnt,
                                              int g, int lane,
                                              const float* __restrict__ W,
                                              float* __restrict__ A) {
    const float4* wl = (const float4*)(W + lane * 4);
    #pragma unroll
    for (int j = 0; j < 7; ++j) {
        float4 w0 = wl[j * (F_DIM / 4)];        // W[j][4*lane ..]
        float4 w1 = wl[j * (F_DIM / 4) + 64];   // W[j][256 + 4*lane ..]
        float v = sa[0] * w0.x + sa[1] * w0.y + sa[2] * w0.z + sa[3] * w0.w
                + sa[4] * w1.x + sa[5] * w1.y + sa[6] * w1.z + sa[7] * w1.w;
        #pragma unroll
        for (int off = 32; off > 0; off >>= 1)
            v += __shfl_down(v, off, 64);
        if (lane == 0) atomicAdd(A + g * 8 + j, v);
    }
    if (lane == 0) atomicAdd(A + g * 8 + 7, (float)seg_cnt);
    #pragma unroll
    for (int k = 0; k < 8; ++k) sa[k] = 0.0f;
}

// DRAM-front streaming: block b owns a CONTIGUOUS chunk of C=49 rows; wave j
// (j=0..3) processes local rows j, j+4, j+8,... So at step t the block's four
// waves together read rows 4t..4t+3 — one dense contiguous 8 KB front. The
// grid presents 2048 coherent streams instead of 8192 independent ones (the
// suspected cause of the 2.5 TB/s plateau: too many simultaneously-open DRAM
// rows). Each 2 KB DRAM row is still opened once and fully consumed.
// Hot loop: 8 raw adds/row ((sum x)·W == sum(x·W)); W applied at flush only.
// Depth-2 pipeline with statically-named registers (runtime-indexed arrays
// spill — round 2's 235 MB scratch lesson). No occupancy forcing.
__global__ __launch_bounds__(256) void node_accum_kernel(
        const float* __restrict__ x, const int* __restrict__ batch,
        const float* __restrict__ W, float* __restrict__ A, int N) {
    const int lane = threadIdx.x & 63;
    const int wj   = threadIdx.x >> 6;                  // wave in block, 0..3
    const int C = (N + gridDim.x - 1) / gridDim.x;      // 49 for 2048 blocks
    const int base = blockIdx.x * C;
    const int len = min(N - base, C);
    if (len <= 0 || wj >= len) return;

    // Block-contiguous id load: every wave loads the same 64 ids (L1-hot).
    int g_l = batch[base + min(lane, len - 1)];

    const int T = (len - wj + 3) >> 2;      // valid iterations for this wave
    const int rmax = wj + 4 * (T - 1);      // last valid local row index

    const float* xb = x + (size_t)base * F_DIM + lane * 4;

    // Preload rows wj and wj+4 (clamped to rmax; duplicates are L1 re-hits).
    const float* p0 = xb + (size_t)wj * F_DIM;
    const float* p1 = xb + (size_t)min(wj + 4, rmax) * F_DIM;
    float4 a0 = ((const float4*)p0)[0];
    float4 c0 = *(const float4*)(p0 + F_DIM / 2);
    float4 a1 = ((const float4*)p1)[0];
    float4 c1 = *(const float4*)(p1 + F_DIM / 2);

    float sa[8];
    #pragma unroll
    for (int k = 0; k < 8; ++k) sa[k] = 0.0f;
    int seg_cnt = 0;
    int g_cur = __shfl(g_l, wj, 64);

    for (int t = 0; t < T; ++t) {
        const int r = wj + 4 * t;
        // Issue row r+8 (depth-2 prefetch, clamped).
        const float* p2 = xb + (size_t)min(r + 8, rmax) * F_DIM;
        float4 na = ((const float4*)p2)[0];
        float4 nc = *(const float4*)(p2 + F_DIM / 2);

        sa[0] += a0.x; sa[1] += a0.y; sa[2] += a0.z; sa[3] += a0.w;
        sa[4] += c0.x; sa[5] += c0.y; sa[6] += c0.z; sa[7] += c0.w;
        ++seg_cnt;

        // Wave-uniform segment bookkeeping (r, T, g_cur uniform per wave).
        bool last = (r + 4 > rmax);
        int g_next = g_cur;
        if (!last) g_next = __shfl(g_l, r + 4, 64);
        if (last || g_next != g_cur) {
            flush_segment(sa, seg_cnt, g_cur, lane, W, A);
            seg_cnt = 0;
            g_cur = g_next;
        }

        a0 = a1; c0 = c1; a1 = na; c1 = nc;
    }
}

__global__ void finalize_kernel(const float* __restrict__ A,
                                const float* __restrict__ b,
                                float* __restrict__ out) {
    int idx = blockIdx.x * blockDim.x + threadIdx.x;
    if (idx >= NUM_GRAPHS * 7) return;
    int g = idx / 7;
    int j = idx - g * 7;
    float cnt = A[g * 8 + 7];
    out[idx] = A[g * 8 + j] / fmaxf(cnt, 1.0f) + b[j];
}

extern "C" void kernel_launch(void* const* d_in, const int* in_sizes, int n_in,
                              void* d_out, int out_size, void* d_ws, size_t ws_size,
                              hipStream_t stream) {
    // Input order: x[100000,512] f32, edge_index (UNUSED), edge_attr (UNUSED),
    // batch_size[100000] int, W[7,512] f32, b[7] f32.
    const float* x     = (const float*)d_in[0];
    const int*   batch = (const int*)d_in[3];
    const float* W     = (const float*)d_in[4];
    const float* b     = (const float*)d_in[5];
    float* out = (float*)d_out;
    float* A   = (float*)d_ws;           // 1024*8 floats = 32 KB
    const int N = in_sizes[3];           // 100000 nodes

    const int ws_elems = NUM_GRAPHS * 8;
    zero_ws_kernel<<<(ws_elems + 255) / 256, 256, 0, stream>>>(A, ws_elems);

    // 2048 blocks * 256 thr; block = one contiguous 49-row chunk streamed by
    // a 4-wave-wide dense front (8 KB per step). 8 blocks/CU if VGPR <= 64.
    node_accum_kernel<<<2048, 256, 0, stream>>>(x, batch, W, A, N);

    finalize_kernel<<<(NUM_GRAPHS * 7 + 255) / 256, 256, 0, stream>>>(A, b, out);
}